// Round 1
// baseline (87.717 us; speedup 1.0000x reference)
//
#include <hip/hip_runtime.h>

#define K3 30  // 3 * K gumbel samples per node

// One block per graph segment. 256 threads.
// Pass 1: per-thread partial sums of exp(gumbel + x) per column (30 register
//         accumulators, statically indexed), then wave shfl_xor butterfly +
//         LDS cross-wave reduce -> log(denom_j) per column.
// Pass 2: re-read rows (L2/L3-hot), out[n] = exp(x + max_j(g_j - log denom_j)).
__global__ __launch_bounds__(256) void gnn_sample_concrete_kernel(
    const float* __restrict__ x,
    const float* __restrict__ uniforms,
    const int* __restrict__ ptr,
    float* __restrict__ out)
{
    const int g = blockIdx.x;
    const int start = ptr[g];
    const int end = ptr[g + 1];
    const int len = end - start;
    if (len <= 0) return;  // uniform across block: empty segment (duplicate cuts)

    const int tid = threadIdx.x;

    float sacc[K3];
#pragma unroll
    for (int j = 0; j < K3; ++j) sacc[j] = 0.0f;

    const int iters = (len + 255) >> 8;

    // ---- Pass 1: column-wise sum of exp(gumbel + x) over the segment ----
    for (int it = 0; it < iters; ++it) {
        const int n = start + it * 256 + tid;
        if (n < end) {
            const float xv = x[n];
            const float2* row =
                reinterpret_cast<const float2*>(uniforms + (size_t)n * K3);
#pragma unroll
            for (int k = 0; k < 15; ++k) {
                float2 u = row[k];
                float g0 = -__logf(-__logf(u.x));
                float g1 = -__logf(-__logf(u.y));
                sacc[2 * k]     += __expf(g0 + xv);
                sacc[2 * k + 1] += __expf(g1 + xv);
            }
        }
    }

    // ---- Wave-level butterfly reduce (64 lanes) ----
#pragma unroll
    for (int j = 0; j < K3; ++j) {
        float v = sacc[j];
#pragma unroll
        for (int off = 32; off >= 1; off >>= 1)
            v += __shfl_xor(v, off, 64);
        sacc[j] = v;
    }

    // ---- Cross-wave reduce via LDS, then log ----
    __shared__ float partial[4][K3];
    __shared__ float lsum[K3];
    const int wave = tid >> 6;
    const int lane = tid & 63;
    if (lane == 0) {
#pragma unroll
        for (int j = 0; j < K3; ++j) partial[wave][j] = sacc[j];
    }
    __syncthreads();
    if (tid < K3) {
        float s = partial[0][tid] + partial[1][tid] + partial[2][tid] +
                  partial[3][tid];
        lsum[tid] = __logf(s);
    }
    __syncthreads();

    float ls[K3];
#pragma unroll
    for (int j = 0; j < K3; ++j) ls[j] = lsum[j];

    // ---- Pass 2: out[n] = exp(x + max_j (g_j - log denom_j)) ----
    for (int it = 0; it < iters; ++it) {
        const int n = start + it * 256 + tid;
        if (n < end) {
            const float xv = x[n];
            const float2* row =
                reinterpret_cast<const float2*>(uniforms + (size_t)n * K3);
            float best = -3.0e38f;
#pragma unroll
            for (int k = 0; k < 15; ++k) {
                float2 u = row[k];
                float g0 = -__logf(-__logf(u.x));
                float g1 = -__logf(-__logf(u.y));
                best = fmaxf(best,
                             fmaxf(g0 - ls[2 * k], g1 - ls[2 * k + 1]));
            }
            out[n] = __expf(best + xv);
        }
    }
}

extern "C" void kernel_launch(void* const* d_in, const int* in_sizes, int n_in,
                              void* d_out, int out_size, void* d_ws, size_t ws_size,
                              hipStream_t stream) {
    const float* x        = (const float*)d_in[0];
    const float* uniforms = (const float*)d_in[1];
    const int*   ptr      = (const int*)d_in[2];
    float* out = (float*)d_out;

    const int B = in_sizes[2] - 1;  // number of graphs (ptr has B+1 entries)

    gnn_sample_concrete_kernel<<<B, 256, 0, stream>>>(x, uniforms, ptr, out);
}

// Round 3
// 80.568 us; speedup vs baseline: 1.0887x; 1.0887x over previous
//
#include <hip/hip_runtime.h>

#define K3 30  // 3*K columns per node
#define KP 15  // float2 pairs per row

// Raw gfx950 transcendental instructions (v_log_f32 / v_exp_f32).
// Safe here: u in [1e-6, 1-1e-6] => all args well inside f32 range.
__device__ __forceinline__ float hw_log2(float a) {
    return __builtin_amdgcn_logf(a);
}
__device__ __forceinline__ float hw_exp2(float a) {
    return __builtin_amdgcn_exp2f(a);
}

// One WAVE per graph segment (4 waves / 256-thread block, 1024 blocks -> grid
// fully resident: 4 blocks/CU, 16 waves/CU, zero __syncthreads, zero LDS).
//
// Log2-domain math:
//   t = log2(-log2(u))            (2 x v_log_f32, neg via input modifier)
//   e = exp(g + x) = exp2(xe - t) where xe = x*log2e + log2e*(-ln ln 2)
//   denom_j = sum_n e_nj ; lw_j = log2(denom_j)
//   out = max_j e_j/denom_j = exp2(xe - min_j (t_j + lw_j))
__global__ __launch_bounds__(256) void gnn_sample_concrete_kernel(
    const float* __restrict__ x,
    const float* __restrict__ uniforms,
    const int* __restrict__ ptr,
    float* __restrict__ out)
{
    const int wave = threadIdx.x >> 6;
    const int lane = threadIdx.x & 63;
    const int g = (blockIdx.x << 2) + wave;   // 1024 blocks * 4 waves = 4096 graphs

    const int start = ptr[g];
    const int end   = ptr[g + 1];
    if (end <= start) return;                 // wave-uniform (empty segment)

    float acc[K3];
#pragma unroll
    for (int j = 0; j < K3; ++j) acc[j] = 0.0f;

    const int iters = (end - start + 63) >> 6;

    // ---- Pass 1: per-column sums of exp2(xe - t) over the segment ----
    for (int it = 0; it < iters; ++it) {
        const int n = start + (it << 6) + lane;
        if (n < end) {
            const float xe = fmaf(x[n], 1.44269504f, 0.52876637f);
            const float2* row =
                reinterpret_cast<const float2*>(uniforms + (size_t)n * K3);
#pragma unroll
            for (int k = 0; k < KP; ++k) {
                float2 u = row[k];
                float t0 = hw_log2(-hw_log2(u.x));
                float t1 = hw_log2(-hw_log2(u.y));
                acc[2 * k]     += hw_exp2(xe - t0);
                acc[2 * k + 1] += hw_exp2(xe - t1);
            }
        }
    }

    // ---- In-wave butterfly allreduce per column, then lw_j = log2(denom_j) ----
#pragma unroll
    for (int j = 0; j < K3; ++j) {
        float v = acc[j];
#pragma unroll
        for (int off = 1; off < 64; off <<= 1)
            v += __shfl_xor(v, off, 64);
        acc[j] = hw_log2(v);
    }

    // ---- Pass 2: out[n] = exp2(xe - min_j (t_j + lw_j)) (segment is L2-hot) ----
    for (int it = 0; it < iters; ++it) {
        const int n = start + (it << 6) + lane;
        if (n < end) {
            const float xe = fmaf(x[n], 1.44269504f, 0.52876637f);
            const float2* row =
                reinterpret_cast<const float2*>(uniforms + (size_t)n * K3);
            float mn = 3.0e38f;
#pragma unroll
            for (int k = 0; k < KP; ++k) {
                float2 u = row[k];
                float t0 = hw_log2(-hw_log2(u.x));
                float t1 = hw_log2(-hw_log2(u.y));
                mn = fminf(mn, fminf(t0 + acc[2 * k], t1 + acc[2 * k + 1]));
            }
            out[n] = hw_exp2(xe - mn);
        }
    }
}

extern "C" void kernel_launch(void* const* d_in, const int* in_sizes, int n_in,
                              void* d_out, int out_size, void* d_ws, size_t ws_size,
                              hipStream_t stream) {
    const float* x        = (const float*)d_in[0];
    const float* uniforms = (const float*)d_in[1];
    const int*   ptr      = (const int*)d_in[2];
    float* out = (float*)d_out;

    const int B = in_sizes[2] - 1;            // 4096 graphs
    const int blocks = (B + 3) / 4;           // 4 graphs (waves) per block

    gnn_sample_concrete_kernel<<<blocks, 256, 0, stream>>>(x, uniforms, ptr, out);
}